// Round 12
// baseline (437.195 us; speedup 1.0000x reference)
//
#include <hip/hip_runtime.h>

#define NTOK 8192
#define DDIM 1024
#define HDIM 2048
#define NEXP 8
#define BM 288
#define NRMAX 29   // ceil(8192/288) -> grid covers any gating skew

typedef __attribute__((ext_vector_type(8))) short short8;
typedef __attribute__((ext_vector_type(4))) float f32x4;

static __device__ __forceinline__ unsigned short f2bf(float f){
  unsigned u = __builtin_bit_cast(unsigned, f);
  u += 0x7fffu + ((u >> 16) & 1u);
  return (unsigned short)(u >> 16);
}
static __device__ __forceinline__ float bf2f(unsigned short s){
  unsigned u = ((unsigned)s) << 16;
  return __builtin_bit_cast(float, u);
}

// async global->LDS, 16B per lane. LDS dest = wave-uniform base + lane*16.
static __device__ __forceinline__ void gload16(const void* g, void* l){
  __builtin_amdgcn_global_load_lds((const __attribute__((address_space(1))) void*)g,
                                   (__attribute__((address_space(3))) void*)l, 16, 0, 0);
}

// ---------------- transpose + f32->bf16: src [R][C] f32 -> dst [C][R] bf16, per expert (z)
__global__ __launch_bounds__(256) void transpose_cvt_kernel(const float* __restrict__ src,
    unsigned short* __restrict__ dst, int R, int C){
  int e = blockIdx.z;
  src += (size_t)e * R * C;
  dst += (size_t)e * R * C;
  __shared__ float tile[32][33];
  int c0 = blockIdx.x * 32, r0 = blockIdx.y * 32;
  int t = threadIdx.x;
  {
    int lr = t >> 3, lc = (t & 7) * 4;
    float4 v = *(const float4*)&src[(size_t)(r0 + lr) * C + c0 + lc];
    tile[lr][lc + 0] = v.x; tile[lr][lc + 1] = v.y;
    tile[lr][lc + 2] = v.z; tile[lr][lc + 3] = v.w;
  }
  __syncthreads();
  {
    int lc = t >> 3, lr = (t & 7) * 4;
    ushort4 o;
    o.x = f2bf(tile[lr + 0][lc]);
    o.y = f2bf(tile[lr + 1][lc]);
    o.z = f2bf(tile[lr + 2][lc]);
    o.w = f2bf(tile[lr + 3][lc]);
    *(ushort4*)&dst[(size_t)(c0 + lc) * R + r0 + lr] = o;
  }
}

// ---------------- gating (fused x->bf16 convert), NO atomics: writes se/sw only.
__global__ __launch_bounds__(256) void gate_kernel(const float* __restrict__ x,
    const float* __restrict__ Wg, const float* __restrict__ bg,
    unsigned short* __restrict__ xbf,
    int* __restrict__ se, float* __restrict__ sw){
  int lane = threadIdx.x & 63;
  int n = blockIdx.x * 4 + (threadIdx.x >> 6);
  const float* xr = x + (size_t)n * DDIM + lane * 16;
  float vv[16];
  #pragma unroll
  for(int i = 0; i < 4; i++){
    float4 v4 = *(const float4*)(xr + i * 4);
    vv[i*4+0] = v4.x; vv[i*4+1] = v4.y; vv[i*4+2] = v4.z; vv[i*4+3] = v4.w;
  }
  {  // packed bf16 store: 32 B per lane
    uint4 p0, p1;
    unsigned pk[8];
    #pragma unroll
    for(int j = 0; j < 8; j++)
      pk[j] = (unsigned)f2bf(vv[2*j]) | ((unsigned)f2bf(vv[2*j+1]) << 16);
    p0.x = pk[0]; p0.y = pk[1]; p0.z = pk[2]; p0.w = pk[3];
    p1.x = pk[4]; p1.y = pk[5]; p1.z = pk[6]; p1.w = pk[7];
    unsigned short* xw = xbf + (size_t)n * DDIM + lane * 16;
    *(uint4*)xw = p0;
    *(uint4*)(xw + 8) = p1;
  }
  float acc[8] = {0,0,0,0,0,0,0,0};
  #pragma unroll
  for(int j = 0; j < 16; j++){
    const float4* wg = (const float4*)&Wg[(lane * 16 + j) * NEXP];
    float4 a = wg[0], b = wg[1];
    float xv = vv[j];
    acc[0] += xv * a.x; acc[1] += xv * a.y; acc[2] += xv * a.z; acc[3] += xv * a.w;
    acc[4] += xv * b.x; acc[5] += xv * b.y; acc[6] += xv * b.z; acc[7] += xv * b.w;
  }
  #pragma unroll
  for(int e = 0; e < 8; e++){
    #pragma unroll
    for(int o = 32; o; o >>= 1) acc[e] += __shfl_xor(acc[e], o);
  }
  float l[8];
  #pragma unroll
  for(int e = 0; e < 8; e++) l[e] = acc[e] + bg[e];
  int i0 = 0; float l0 = l[0];
  #pragma unroll
  for(int e = 1; e < 8; e++) if(l[e] > l0){ l0 = l[e]; i0 = e; }
  int i1 = -1; float l1 = -3.4e38f;
  #pragma unroll
  for(int e = 0; e < 8; e++) if(e != i0 && l[e] > l1){ l1 = l[e]; i1 = e; }
  float w0 = 1.0f / (1.0f + expf(l1 - l0));   // = softmax over the 2 selected logits
  float w1 = 1.0f - w0;
  if(lane == 0){
    se[2*n] = i0; se[2*n+1] = i1;
    sw[2*n] = w0; sw[2*n+1] = w1;
  }
}

// ---------------- build per-expert compact lists: ordered compaction, no global atomics.
__global__ __launch_bounds__(1024) void build_lists_kernel(const int* __restrict__ se,
    int* __restrict__ toklist, int* __restrict__ sp, int* __restrict__ cnt){
  int e = blockIdx.x;
  int t = threadIdx.x;
  int lane = t & 63, wv = t >> 6;   // 16 waves
  __shared__ int wsum[16];
  __shared__ int runbase;
  if(t == 0) runbase = 0;
  __syncthreads();
  for(int base = 0; base < 2 * NTOK; base += 1024){
    int g = base + t;
    bool mine = (se[g] == e);
    unsigned long long m = __ballot(mine);
    int wcnt = __popcll(m);
    int before = __popcll(m & ((1ull << lane) - 1ull));
    if(lane == 0) wsum[wv] = wcnt;
    __syncthreads();
    int wbase = 0, total = 0;
    #pragma unroll
    for(int i = 0; i < 16; i++){
      int s = wsum[i];
      wbase += (i < wv) ? s : 0;
      total += s;
    }
    int pos = runbase + wbase + before;
    if(mine){
      toklist[e * NTOK + pos] = g >> 1;
      sp[g] = pos;
    }
    __syncthreads();
    if(t == 0) runbase += total;
    __syncthreads();
  }
  if(t == 0) cnt[e] = runbase;
}

// ---------------- permute xbf into compact slot order: xperm[slot] = xbf[tok[slot]]
// One block per slot, 128 threads x 16B = 2KB row. Gather happens ONCE here,
// so gemm1's 8x-rereads of A become fully contiguous.
__global__ __launch_bounds__(128) void xperm_kernel(const unsigned short* __restrict__ xbf,
    const int* __restrict__ cnt, const int* __restrict__ toklist,
    unsigned short* __restrict__ xperm){
  int s = blockIdx.x;
  int pre = 0, e = 0;
  #pragma unroll
  for(int i = 1; i < NEXP; i++){
    pre += cnt[i-1];
    if(s >= pre) e = i;
  }
  int ebase = 0;
  #pragma unroll
  for(int i = 0; i < NEXP; i++) ebase += (i < e) ? cnt[i] : 0;
  int tok = toklist[e * NTOK + (s - ebase)];
  const uint4* src = (const uint4*)(xbf + (size_t)tok * DDIM);
  uint4* dst = (uint4*)(xperm + (size_t)s * DDIM);
  dst[threadIdx.x] = src[threadIdx.x];
}

#define ADST(buf, i) ((char*)&A_s[buf][0] + (i)*8192 + wbase)
#define BDST(buf, i) ((char*)&B_s[buf][0] + (i)*8192 + wbase)

// 10-phase K-loop (5 phases per BK=64 K-tile, BM=288), counted vmcnt, 16x16x32 MFMA.
// Phase q computes m-frags {2q, 2q+1} (q=4: frag 8 only). B pre-read ph0.
// A staged CONCENTRATED in ph0/ph1 (max latency cover); B(t+2) spread ph2-4.
// Per-wave ledger: at boundary every wave's newest 4 in-flight = B(t+2) -> vmcnt(4).
#define KLOOP_PIPE(NT)                                                                \
  { /* prologue: B(0), A(0) -> buf0 ; B(1) -> buf1 */                                 \
    _Pragma("unroll")                                                                 \
    for(int i = 0; i < 4; i++) gload16(bptr[i], BDST(0, i));                          \
    _Pragma("unroll")                                                                 \
    for(int i = 0; i < 4; i++) gload16(aptr[i], ADST(0, i));                          \
    if(ahalf) gload16(aptr[4], ADST(0, 4));                                           \
    _Pragma("unroll")                                                                 \
    for(int i = 0; i < 4; i++) gload16(bptr[i] + 64, BDST(1, i));                     \
    __builtin_amdgcn_sched_barrier(0);                                                \
    asm volatile("s_waitcnt vmcnt(4)" ::: "memory");                                  \
    __builtin_amdgcn_sched_barrier(0);                                                \
    __builtin_amdgcn_s_barrier();                                                     \
    __builtin_amdgcn_sched_barrier(0);                                                \
  }                                                                                   \
  const int ch0 = ((fg) ^ (fr & 7)) << 3;                                             \
  const int ch1 = ((4 + fg) ^ (fr & 7)) << 3;                                         \
  for(int kt = 0; kt < (NT); ++kt){                                                   \
    const int p = kt & 1;                                                             \
    const unsigned short* Ab = &A_s[p][0];                                            \
    const unsigned short* Bb = &B_s[p][0];                                            \
    short8 bq[4][2];                                                                  \
    _Pragma("unroll")                                                                 \
    for(int q = 0; q < 5; ++q){                                                       \
      const int nmm = (q == 4) ? 1 : 2;                                               \
      short8 af[2][2];                                                                \
      _Pragma("unroll")                                                               \
      for(int mm = 0; mm < 2; ++mm){                                                  \
        if(mm < nmm){                                                                 \
          int row = wr*144 + (q*2 + mm)*16 + fr;                                      \
          af[mm][0] = *(const short8*)&Ab[row*64 + ch0];                              \
          af[mm][1] = *(const short8*)&Ab[row*64 + ch1];                              \
        }                                                                             \
      }                                                                               \
      if(q == 0){                                                                     \
        _Pragma("unroll")                                                             \
        for(int nn = 0; nn < 4; ++nn){                                                \
          int col = wc*64 + nn*16 + fr;                                               \
          bq[nn][0] = *(const short8*)&Bb[col*64 + ch0];                              \
          bq[nn][1] = *(const short8*)&Bb[col*64 + ch1];                              \
        }                                                                             \
      }                                                                               \
      if(q == 0 && kt+1 < (NT)){                                                      \
        gload16(aptr[0] + (kt+1)*64, ADST(p^1, 0));                                   \
        gload16(aptr[1] + (kt+1)*64, ADST(p^1, 1));                                   \
        gload16(aptr[2] + (kt+1)*64, ADST(p^1, 2));                                   \
      } else if(q == 1 && kt+1 < (NT)){                                               \
        gload16(aptr[3] + (kt+1)*64, ADST(p^1, 3));                                   \
        if(ahalf) gload16(aptr[4] + (kt+1)*64, ADST(p^1, 4));                         \
      } else if(q == 2 && kt+2 < (NT)){                                               \
        gload16(bptr[0] + (kt+2)*64, BDST(p, 0));                                     \
      } else if(q == 3 && kt+2 < (NT)){                                               \
        gload16(bptr[1] + (kt+2)*64, BDST(p, 1));                                     \
        gload16(bptr[2] + (kt+2)*64, BDST(p, 2));                                     \
      } else if(q == 4 && kt+2 < (NT)){                                               \
        gload16(bptr[3] + (kt+2)*64, BDST(p, 3));                                     \
      }                                                                               \
      __builtin_amdgcn_sched_barrier(0);                                              \
      __builtin_amdgcn_s_barrier();                                                   \
      __builtin_amdgcn_sched_barrier(0);                                              \
      __builtin_amdgcn_s_setprio(1);                                                  \
      _Pragma("unroll")                                                               \
      for(int mm = 0; mm < 2; ++mm){                                                  \
        if(mm < nmm){                                                                 \
          _Pragma("unroll")                                                           \
          for(int nn = 0; nn < 4; ++nn){                                              \
            acc[q*2+mm][nn] = __builtin_amdgcn_mfma_f32_16x16x32_bf16(af[mm][0], bq[nn][0], acc[q*2+mm][nn], 0, 0, 0); \
            acc[q*2+mm][nn] = __builtin_amdgcn_mfma_f32_16x16x32_bf16(af[mm][1], bq[nn][1], acc[q*2+mm][nn], 0, 0, 0); \
          }                                                                           \
        }                                                                             \
      }                                                                               \
      __builtin_amdgcn_s_setprio(0);                                                  \
      __builtin_amdgcn_sched_barrier(0);                                              \
      if(q == 4){                                                                     \
        if(kt < (NT)-2)      { asm volatile("s_waitcnt vmcnt(4)" ::: "memory"); }     \
        else if(kt < (NT)-1) { asm volatile("s_waitcnt vmcnt(0)" ::: "memory"); }     \
      }                                                                               \
      __builtin_amdgcn_s_barrier();                                                   \
      __builtin_amdgcn_sched_barrier(0);                                              \
    }                                                                                 \
  }

static __device__ __forceinline__ int base_of(const int* __restrict__ cnt, int e){
  int b = 0;
  #pragma unroll
  for(int i = 0; i < NEXP; i++) b += (i < e) ? cnt[i] : 0;
  return b;
}

// ---------------- grouped GEMM1: 288x256 tile, 8 waves, 5-phase/K-tile pipeline
// A read CONTIGUOUSLY from xperm (slot order). 1D grid, expert-per-XCD decode.
__global__ __launch_bounds__(512) void gemm1_kernel(const unsigned short* __restrict__ xperm,
    const unsigned short* __restrict__ W1T, const float* __restrict__ b1,
    const int* __restrict__ cnt, unsigned short* __restrict__ hbuf){
  int d = blockIdx.x;
  int e = d & 7;
  int cnt_e = cnt[e];
  int row0 = (d >> 6) * BM;
  if(row0 >= cnt_e) return;
  int col0 = ((d >> 3) & 7) * 256;
  int ebase = base_of(cnt, e);
  __shared__ __align__(16) unsigned short A_s[2][BM * 64];    // 2 x 36 KB
  __shared__ __align__(16) unsigned short B_s[2][256 * 64];   // 2 x 32 KB
  int t = threadIdx.x;
  int lane = t & 63, w = t >> 6;
  int wr = w >> 2, wc = w & 3;            // wave sub-tile: rows wr*144, cols wc*64
  int fr = lane & 15, fg = lane >> 4;
  int srow = t >> 3;
  int schunk = ((t & 7) ^ (srow & 7)) * 8;
  bool ahalf = t < 256;
  const unsigned short* W1e = W1T + (size_t)e * HDIM * DDIM;
  const unsigned short* aptr[5];
  const unsigned short* bptr[4];
  #pragma unroll
  for(int i = 0; i < 4; i++)
    aptr[i] = xperm + (size_t)(ebase + row0 + i * 64 + srow) * DDIM + schunk;
  aptr[4] = xperm + (size_t)(ebase + row0 + 256 + (ahalf ? srow : 0)) * DDIM + schunk;
  #pragma unroll
  for(int i = 0; i < 4; i++)
    bptr[i] = W1e + (size_t)(col0 + i * 64 + srow) * DDIM + schunk;
  unsigned wbase = (unsigned)(w << 10);   // wave-uniform LDS byte base
  f32x4 acc[9][4] = {};
  KLOOP_PIPE(DDIM / 64)
  int slot0 = ebase + row0;
  #pragma unroll
  for(int m = 0; m < 9; m++){
    #pragma unroll
    for(int i = 0; i < 4; i++){
      int rr = wr*144 + m*16 + fg*4 + i;     // D: row=(lane>>4)*4+i, col=lane&15
      if(row0 + rr < cnt_e){
        size_t rowoff = (size_t)(slot0 + rr) * HDIM;
        #pragma unroll
        for(int nn = 0; nn < 4; nn++){
          int c = col0 + wc*64 + nn*16 + fr;
          float v = acc[m][nn][i] + b1[e * HDIM + c];
          hbuf[rowoff + c] = f2bf(v);
        }
      }
    }
  }
}

// ---------------- rowwise LayerNorm + exact GELU, flattened over compact slots
__global__ __launch_bounds__(256) void ln_gelu_kernel(unsigned short* __restrict__ hbuf,
    const float* __restrict__ ln_g, const float* __restrict__ ln_b,
    const int* __restrict__ cnt){
  int s = blockIdx.x;              // slot 0..2*NTOK-1, always valid (sum cnt == 2*NTOK)
  int pre = 0, e = 0;
  #pragma unroll
  for(int i = 1; i < NEXP; i++){
    pre += cnt[i-1];
    if(s >= pre) e = i;
  }
  size_t off = (size_t)s * HDIM;
  int t = threadIdx.x;
  uint4 pk = *(const uint4*)&hbuf[off + t * 8];
  float v[8];
  {
    unsigned uu[4] = {pk.x, pk.y, pk.z, pk.w};
    #pragma unroll
    for(int j = 0; j < 4; j++){
      v[2*j]   = bf2f((unsigned short)(uu[j] & 0xffffu));
      v[2*j+1] = bf2f((unsigned short)(uu[j] >> 16));
    }
  }
  float sm = 0.f, ss = 0.f;
  #pragma unroll
  for(int j = 0; j < 8; j++){ sm += v[j]; ss += v[j] * v[j]; }
  #pragma unroll
  for(int o = 32; o; o >>= 1){ sm += __shfl_xor(sm, o); ss += __shfl_xor(ss, o); }
  __shared__ float red[8];
  if((t & 63) == 0){ red[t >> 6] = sm; red[4 + (t >> 6)] = ss; }
  __syncthreads();
  sm = red[0] + red[1] + red[2] + red[3];
  ss = red[4] + red[5] + red[6] + red[7];
  float mean = sm * (1.0f / HDIM);
  float var  = ss * (1.0f / HDIM) - mean * mean;
  float rstd = rsqrtf(var + 1e-5f);
  const float* g  = ln_g + e * HDIM + t * 8;
  const float* bb = ln_b + e * HDIM + t * 8;
  unsigned ou[4];
  #pragma unroll
  for(int j = 0; j < 4; j++){
    float y0 = (v[2*j]   - mean) * rstd * g[2*j]   + bb[2*j];
    float y1 = (v[2*j+1] - mean) * rstd * g[2*j+1] + bb[2*j+1];
    y0 = 0.5f * y0 * (1.0f + erff(y0 * 0.70710678118654752f));
    y1 = 0.5f * y1 * (1.0f + erff(y1 * 0.70710678118654752f));
    ou[j] = (unsigned)f2bf(y0) | ((unsigned)f2bf(y1) << 16);
  }
  uint4 o4; o4.x = ou[0]; o4.y = ou[1]; o4.z = ou[2]; o4.w = ou[3];
  *(uint4*)&hbuf[off + t * 8] = o4;
}

// ---------------- grouped GEMM2: 288x256 tile, 8 waves, 5-phase/K-tile; linear bf16 store
__global__ __launch_bounds__(512) void gemm2_kernel(const unsigned short* __restrict__ hbuf,
    const unsigned short* __restrict__ W2T, const float* __restrict__ b2,
    const int* __restrict__ cnt, unsigned short* __restrict__ eobuf){
  int d = blockIdx.x;
  int e = d & 7;
  int cnt_e = cnt[e];
  int row0 = (d >> 6) * BM;
  if(row0 >= cnt_e) return;
  int col0 = ((d >> 3) & 7) * 256;
  int ebase = base_of(cnt, e);
  __shared__ __align__(16) unsigned short A_s[2][BM * 64];
  __shared__ __align__(16) unsigned short B_s[2][256 * 64];
  int t = threadIdx.x;
  int lane = t & 63, w = t >> 6;
  int wr = w >> 2, wc = w & 3;
  int fr = lane & 15, fg = lane >> 4;
  int srow = t >> 3;
  int schunk = ((t & 7) ^ (srow & 7)) * 8;
  bool ahalf = t < 256;
  const unsigned short* W2e = W2T + (size_t)e * HDIM * HDIM;
  const unsigned short* aptr[5];
  const unsigned short* bptr[4];
  #pragma unroll
  for(int i = 0; i < 4; i++)
    aptr[i] = hbuf + (size_t)(ebase + row0 + i * 64 + srow) * HDIM + schunk;
  aptr[4] = hbuf + (size_t)(ebase + row0 + 256 + (ahalf ? srow : 0)) * HDIM + schunk;
  #pragma unroll
  for(int i = 0; i < 4; i++)
    bptr[i] = W2e + (size_t)(col0 + i * 64 + srow) * HDIM + schunk;
  unsigned wbase = (unsigned)(w << 10);
  f32x4 acc[9][4] = {};
  KLOOP_PIPE(HDIM / 64)
  int slot0 = ebase + row0;
  #pragma unroll
  for(int m = 0; m < 9; m++){
    #pragma unroll
    for(int i = 0; i < 4; i++){
      int rr = wr*144 + m*16 + fg*4 + i;
      if(row0 + rr < cnt_e){
        size_t rowoff = (size_t)(slot0 + rr) * HDIM;
        #pragma unroll
        for(int nn = 0; nn < 4; nn++){
          int c = col0 + wc*64 + nn*16 + fr;
          float v = acc[m][nn][i] + b2[e * HDIM + c];
          eobuf[rowoff + c] = f2bf(v);
        }
      }
    }
  }
}

// ---------------- combine: out[n] = w0*eo[slot0] + w1*eo[slot1]
__global__ __launch_bounds__(256) void combine_kernel(const unsigned short* __restrict__ eobuf,
    const int* __restrict__ cnt, const int* __restrict__ se, const int* __restrict__ sp,
    const float* __restrict__ sw, float* __restrict__ out){
  int n = blockIdx.x, t = threadIdx.x;
  int pre[NEXP];
  {
    int b = 0;
    #pragma unroll
    for(int i = 0; i < NEXP; i++){ pre[i] = b; b += cnt[i]; }
  }
  int e0 = se[2*n], e1 = se[2*n+1];
  int s0 = pre[e0] + sp[2*n];
  int s1 = pre[e1] + sp[2*n+1];
  float w0 = sw[2*n], w1 = sw[2*n+1];
  uint4 p0 = *(const uint4*)&eobuf[(size_t)s0 * HDIM + t * 8];
  uint4 p1 = *(const uint4*)&eobuf[(size_t)s1 * HDIM + t * 8];
  unsigned a[4] = {p0.x, p0.y, p0.z, p0.w};
  unsigned b[4] = {p1.x, p1.y, p1.z, p1.w};
  float o[8];
  #pragma unroll
  for(int j = 0; j < 4; j++){
    o[2*j]   = w0 * bf2f((unsigned short)(a[j] & 0xffffu)) + w1 * bf2f((unsigned short)(b[j] & 0xffffu));
    o[2*j+1] = w0 * bf2f((unsigned short)(a[j] >> 16))     + w1 * bf2f((unsigned short)(b[j] >> 16));
  }
  float4 o0 = {o[0], o[1], o[2], o[3]};
  float4 o1 = {o[4], o[5], o[6], o[7]};
  float* dst = out + (size_t)n * HDIM + t * 8;
  *(float4*)dst = o0;
  *(float4*)(dst + 4) = o1;
}

extern "C" void kernel_launch(void* const* d_in, const int* in_sizes, int n_in,
                              void* d_out, int out_size, void* d_ws, size_t ws_size,
                              hipStream_t stream){
  (void)in_sizes; (void)n_in; (void)out_size; (void)ws_size;
  const float* x   = (const float*)d_in[0];
  const float* W1  = (const float*)d_in[1];
  const float* b1  = (const float*)d_in[2];
  const float* lng = (const float*)d_in[3];
  const float* lnb = (const float*)d_in[4];
  const float* W2  = (const float*)d_in[5];
  const float* b2  = (const float*)d_in[6];
  const float* Wg  = (const float*)d_in[7];
  const float* bg  = (const float*)d_in[8];
  float* out = (float*)d_out;

  char* ws = (char*)d_ws;
  size_t o = 0;
  unsigned short* W1T   = (unsigned short*)(ws + o); o += (size_t)NEXP * HDIM * DDIM * 2;      // 33.5 MB
  unsigned short* W2T   = (unsigned short*)(ws + o); o += (size_t)NEXP * HDIM * HDIM * 2;      // 67 MB
  unsigned short* hbuf  = (unsigned short*)(ws + o); o += (size_t)(NTOK * 2 + 512) * HDIM * 2; // 68 MB
  unsigned short* eobuf = (unsigned short*)(ws + o); o += (size_t)(NTOK * 2 + 512) * HDIM * 2; // 68 MB
  unsigned short* xbf   = (unsigned short*)(ws + o); o += (size_t)NTOK * DDIM * 2;             // 16.8 MB
  unsigned short* xperm = (unsigned short*)(ws + o); o += (size_t)(NTOK * 2 + 512) * DDIM * 2; // 34.6 MB
  int*   cnt     = (int*)(ws + o);   o += 128;
  int*   toklist = (int*)(ws + o);   o += (size_t)NEXP * NTOK * 4;
  int*   se      = (int*)(ws + o);   o += (size_t)NTOK * 2 * 4;
  int*   sp      = (int*)(ws + o);   o += (size_t)NTOK * 2 * 4;
  float* sw      = (float*)(ws + o); o += (size_t)NTOK * 2 * 4;

  transpose_cvt_kernel<<<dim3(HDIM/32, DDIM/32, NEXP), 256, 0, stream>>>(W1, W1T, DDIM, HDIM);
  transpose_cvt_kernel<<<dim3(HDIM/32, HDIM/32, NEXP), 256, 0, stream>>>(W2, W2T, HDIM, HDIM);
  gate_kernel<<<NTOK/4, 256, 0, stream>>>(x, Wg, bg, xbf, se, sw);
  build_lists_kernel<<<NEXP, 1024, 0, stream>>>(se, toklist, sp, cnt);
  xperm_kernel<<<NTOK * 2, 128, 0, stream>>>(xbf, cnt, toklist, xperm);
  // 1D grids: 8 experts x 8 col-blocks x NRMAX row-blocks (live blocks packed at low indices)
  gemm1_kernel<<<8 * 8 * NRMAX, 512, 0, stream>>>(xperm, W1T, b1, cnt, hbuf);
  ln_gelu_kernel<<<NTOK * 2, 256, 0, stream>>>(hbuf, lng, lnb, cnt);
  gemm2_kernel<<<8 * 8 * NRMAX, 512, 0, stream>>>(hbuf, W2T, b2, cnt, eobuf);
  combine_kernel<<<NTOK, 256, 0, stream>>>(eobuf, cnt, se, sp, sw, out);
}

// Round 13
// 415.191 us; speedup vs baseline: 1.0530x; 1.0530x over previous
//
#include <hip/hip_runtime.h>

#define NTOK 8192
#define DDIM 1024
#define HDIM 2048
#define NEXP 8
#define BM 288
#define NRMAX 29   // ceil(8192/288) -> grid covers any gating skew

typedef __attribute__((ext_vector_type(8))) short short8;
typedef __attribute__((ext_vector_type(4))) float f32x4;

static __device__ __forceinline__ unsigned short f2bf(float f){
  unsigned u = __builtin_bit_cast(unsigned, f);
  u += 0x7fffu + ((u >> 16) & 1u);
  return (unsigned short)(u >> 16);
}
static __device__ __forceinline__ float bf2f(unsigned short s){
  unsigned u = ((unsigned)s) << 16;
  return __builtin_bit_cast(float, u);
}

// async global->LDS, 16B per lane. LDS dest = wave-uniform base + lane*16.
static __device__ __forceinline__ void gload16(const void* g, void* l){
  __builtin_amdgcn_global_load_lds((const __attribute__((address_space(1))) void*)g,
                                   (__attribute__((address_space(3))) void*)l, 16, 0, 0);
}

// ---------------- fused transpose + f32->bf16 for BOTH weights (one launch)
// y < DDIM/32: W1 [DDIM][HDIM] -> W1T [HDIM][DDIM]; else W2 [HDIM][HDIM] -> W2T.
__global__ __launch_bounds__(256) void transpose_cvt2_kernel(const float* __restrict__ W1,
    const float* __restrict__ W2, unsigned short* __restrict__ W1T,
    unsigned short* __restrict__ W2T){
  int e = blockIdx.z;
  const float* src;
  unsigned short* dst;
  int R, r0;
  if(blockIdx.y < DDIM/32){
    src = W1 + (size_t)e * DDIM * HDIM; dst = W1T + (size_t)e * DDIM * HDIM;
    R = DDIM; r0 = blockIdx.y * 32;
  } else {
    src = W2 + (size_t)e * HDIM * HDIM; dst = W2T + (size_t)e * HDIM * HDIM;
    R = HDIM; r0 = (blockIdx.y - DDIM/32) * 32;
  }
  const int C = HDIM;
  __shared__ float tile[32][33];
  int c0 = blockIdx.x * 32;
  int t = threadIdx.x;
  {
    int lr = t >> 3, lc = (t & 7) * 4;
    float4 v = *(const float4*)&src[(size_t)(r0 + lr) * C + c0 + lc];
    tile[lr][lc + 0] = v.x; tile[lr][lc + 1] = v.y;
    tile[lr][lc + 2] = v.z; tile[lr][lc + 3] = v.w;
  }
  __syncthreads();
  {
    int lc = t >> 3, lr = (t & 7) * 4;
    ushort4 o;
    o.x = f2bf(tile[lr + 0][lc]);
    o.y = f2bf(tile[lr + 1][lc]);
    o.z = f2bf(tile[lr + 2][lc]);
    o.w = f2bf(tile[lr + 3][lc]);
    *(ushort4*)&dst[(size_t)(c0 + lc) * R + r0 + lr] = o;
  }
}

// ---------------- gating (fused x->bf16 convert), NO atomics: writes se/sw only.
__global__ __launch_bounds__(256) void gate_kernel(const float* __restrict__ x,
    const float* __restrict__ Wg, const float* __restrict__ bg,
    unsigned short* __restrict__ xbf,
    int* __restrict__ se, float* __restrict__ sw){
  int lane = threadIdx.x & 63;
  int n = blockIdx.x * 4 + (threadIdx.x >> 6);
  const float* xr = x + (size_t)n * DDIM + lane * 16;
  float vv[16];
  #pragma unroll
  for(int i = 0; i < 4; i++){
    float4 v4 = *(const float4*)(xr + i * 4);
    vv[i*4+0] = v4.x; vv[i*4+1] = v4.y; vv[i*4+2] = v4.z; vv[i*4+3] = v4.w;
  }
  {  // packed bf16 store: 32 B per lane
    uint4 p0, p1;
    unsigned pk[8];
    #pragma unroll
    for(int j = 0; j < 8; j++)
      pk[j] = (unsigned)f2bf(vv[2*j]) | ((unsigned)f2bf(vv[2*j+1]) << 16);
    p0.x = pk[0]; p0.y = pk[1]; p0.z = pk[2]; p0.w = pk[3];
    p1.x = pk[4]; p1.y = pk[5]; p1.z = pk[6]; p1.w = pk[7];
    unsigned short* xw = xbf + (size_t)n * DDIM + lane * 16;
    *(uint4*)xw = p0;
    *(uint4*)(xw + 8) = p1;
  }
  float acc[8] = {0,0,0,0,0,0,0,0};
  #pragma unroll
  for(int j = 0; j < 16; j++){
    const float4* wg = (const float4*)&Wg[(lane * 16 + j) * NEXP];
    float4 a = wg[0], b = wg[1];
    float xv = vv[j];
    acc[0] += xv * a.x; acc[1] += xv * a.y; acc[2] += xv * a.z; acc[3] += xv * a.w;
    acc[4] += xv * b.x; acc[5] += xv * b.y; acc[6] += xv * b.z; acc[7] += xv * b.w;
  }
  #pragma unroll
  for(int e = 0; e < 8; e++){
    #pragma unroll
    for(int o = 32; o; o >>= 1) acc[e] += __shfl_xor(acc[e], o);
  }
  float l[8];
  #pragma unroll
  for(int e = 0; e < 8; e++) l[e] = acc[e] + bg[e];
  int i0 = 0; float l0 = l[0];
  #pragma unroll
  for(int e = 1; e < 8; e++) if(l[e] > l0){ l0 = l[e]; i0 = e; }
  int i1 = -1; float l1 = -3.4e38f;
  #pragma unroll
  for(int e = 0; e < 8; e++) if(e != i0 && l[e] > l1){ l1 = l[e]; i1 = e; }
  float w0 = 1.0f / (1.0f + expf(l1 - l0));   // = softmax over the 2 selected logits
  float w1 = 1.0f - w0;
  if(lane == 0){
    se[2*n] = i0; se[2*n+1] = i1;
    sw[2*n] = w0; sw[2*n+1] = w1;
  }
}

// ---------------- build per-expert compact lists: ordered compaction, no global atomics.
__global__ __launch_bounds__(1024) void build_lists_kernel(const int* __restrict__ se,
    int* __restrict__ toklist, int* __restrict__ sp, int* __restrict__ cnt){
  int e = blockIdx.x;
  int t = threadIdx.x;
  int lane = t & 63, wv = t >> 6;   // 16 waves
  __shared__ int wsum[16];
  __shared__ int runbase;
  if(t == 0) runbase = 0;
  __syncthreads();
  for(int base = 0; base < 2 * NTOK; base += 1024){
    int g = base + t;
    bool mine = (se[g] == e);
    unsigned long long m = __ballot(mine);
    int wcnt = __popcll(m);
    int before = __popcll(m & ((1ull << lane) - 1ull));
    if(lane == 0) wsum[wv] = wcnt;
    __syncthreads();
    int wbase = 0, total = 0;
    #pragma unroll
    for(int i = 0; i < 16; i++){
      int s = wsum[i];
      wbase += (i < wv) ? s : 0;
      total += s;
    }
    int pos = runbase + wbase + before;
    if(mine){
      toklist[e * NTOK + pos] = g >> 1;
      sp[g] = pos;
    }
    __syncthreads();
    if(t == 0) runbase += total;
    __syncthreads();
  }
  if(t == 0) cnt[e] = runbase;
}

#define ADST(buf, i) ((char*)&A_s[buf][0] + (i)*8192 + wbase)
#define BDST(buf, i) ((char*)&B_s[buf][0] + (i)*8192 + wbase)

// 10-phase K-loop (5 phases per BK=64 K-tile, BM=288), counted vmcnt, 16x16x32 MFMA.
// Phase q computes m-frags {2q, 2q+1} (q=4: frag 8 only). B pre-read ph0.
// A staged CONCENTRATED in ph0/ph1 (max latency cover); B(t+2) spread ph2-4.
// Per-wave ledger: at boundary every wave's newest 4 in-flight = B(t+2) -> vmcnt(4).
#define KLOOP_PIPE(NT)                                                                \
  { /* prologue: B(0), A(0) -> buf0 ; B(1) -> buf1 */                                 \
    _Pragma("unroll")                                                                 \
    for(int i = 0; i < 4; i++) gload16(bptr[i], BDST(0, i));                          \
    _Pragma("unroll")                                                                 \
    for(int i = 0; i < 4; i++) gload16(aptr[i], ADST(0, i));                          \
    if(ahalf) gload16(aptr[4], ADST(0, 4));                                           \
    _Pragma("unroll")                                                                 \
    for(int i = 0; i < 4; i++) gload16(bptr[i] + 64, BDST(1, i));                     \
    __builtin_amdgcn_sched_barrier(0);                                                \
    asm volatile("s_waitcnt vmcnt(4)" ::: "memory");                                  \
    __builtin_amdgcn_sched_barrier(0);                                                \
    __builtin_amdgcn_s_barrier();                                                     \
    __builtin_amdgcn_sched_barrier(0);                                                \
  }                                                                                   \
  const int ch0 = ((fg) ^ (fr & 7)) << 3;                                             \
  const int ch1 = ((4 + fg) ^ (fr & 7)) << 3;                                         \
  for(int kt = 0; kt < (NT); ++kt){                                                   \
    const int p = kt & 1;                                                             \
    const unsigned short* Ab = &A_s[p][0];                                            \
    const unsigned short* Bb = &B_s[p][0];                                            \
    short8 bq[4][2];                                                                  \
    _Pragma("unroll")                                                                 \
    for(int q = 0; q < 5; ++q){                                                       \
      const int nmm = (q == 4) ? 1 : 2;                                               \
      short8 af[2][2];                                                                \
      _Pragma("unroll")                                                               \
      for(int mm = 0; mm < 2; ++mm){                                                  \
        if(mm < nmm){                                                                 \
          int row = wr*144 + (q*2 + mm)*16 + fr;                                      \
          af[mm][0] = *(const short8*)&Ab[row*64 + ch0];                              \
          af[mm][1] = *(const short8*)&Ab[row*64 + ch1];                              \
        }                                                                             \
      }                                                                               \
      if(q == 0){                                                                     \
        _Pragma("unroll")                                                             \
        for(int nn = 0; nn < 4; ++nn){                                                \
          int col = wc*64 + nn*16 + fr;                                               \
          bq[nn][0] = *(const short8*)&Bb[col*64 + ch0];                              \
          bq[nn][1] = *(const short8*)&Bb[col*64 + ch1];                              \
        }                                                                             \
      }                                                                               \
      if(q == 0 && kt+1 < (NT)){                                                      \
        gload16(aptr[0] + (kt+1)*64, ADST(p^1, 0));                                   \
        gload16(aptr[1] + (kt+1)*64, ADST(p^1, 1));                                   \
        gload16(aptr[2] + (kt+1)*64, ADST(p^1, 2));                                   \
      } else if(q == 1 && kt+1 < (NT)){                                               \
        gload16(aptr[3] + (kt+1)*64, ADST(p^1, 3));                                   \
        if(ahalf) gload16(aptr[4] + (kt+1)*64, ADST(p^1, 4));                         \
      } else if(q == 2 && kt+2 < (NT)){                                               \
        gload16(bptr[0] + (kt+2)*64, BDST(p, 0));                                     \
      } else if(q == 3 && kt+2 < (NT)){                                               \
        gload16(bptr[1] + (kt+2)*64, BDST(p, 1));                                     \
        gload16(bptr[2] + (kt+2)*64, BDST(p, 2));                                     \
      } else if(q == 4 && kt+2 < (NT)){                                               \
        gload16(bptr[3] + (kt+2)*64, BDST(p, 3));                                     \
      }                                                                               \
      __builtin_amdgcn_sched_barrier(0);                                              \
      __builtin_amdgcn_s_barrier();                                                   \
      __builtin_amdgcn_sched_barrier(0);                                              \
      __builtin_amdgcn_s_setprio(1);                                                  \
      _Pragma("unroll")                                                               \
      for(int mm = 0; mm < 2; ++mm){                                                  \
        if(mm < nmm){                                                                 \
          _Pragma("unroll")                                                           \
          for(int nn = 0; nn < 4; ++nn){                                              \
            acc[q*2+mm][nn] = __builtin_amdgcn_mfma_f32_16x16x32_bf16(af[mm][0], bq[nn][0], acc[q*2+mm][nn], 0, 0, 0); \
            acc[q*2+mm][nn] = __builtin_amdgcn_mfma_f32_16x16x32_bf16(af[mm][1], bq[nn][1], acc[q*2+mm][nn], 0, 0, 0); \
          }                                                                           \
        }                                                                             \
      }                                                                               \
      __builtin_amdgcn_s_setprio(0);                                                  \
      __builtin_amdgcn_sched_barrier(0);                                              \
      if(q == 4){                                                                     \
        if(kt < (NT)-2)      { asm volatile("s_waitcnt vmcnt(4)" ::: "memory"); }     \
        else if(kt < (NT)-1) { asm volatile("s_waitcnt vmcnt(0)" ::: "memory"); }     \
      }                                                                               \
      __builtin_amdgcn_s_barrier();                                                   \
      __builtin_amdgcn_sched_barrier(0);                                              \
    }                                                                                 \
  }

static __device__ __forceinline__ int base_of(const int* __restrict__ cnt, int e){
  int b = 0;
  #pragma unroll
  for(int i = 0; i < NEXP; i++) b += (i < e) ? cnt[i] : 0;
  return b;
}

// ---------------- grouped GEMM1: 288x256 tile, 8 waves, 5-phase/K-tile pipeline
// A gathered via toklist (xperm reverted: gather is latency-hidden, r12 proved it).
// 1D grid, expert-per-XCD decode: e = d&7 (== XCD), c = (d>>3)&7, r = d>>6.
__global__ __launch_bounds__(512) void gemm1_kernel(const unsigned short* __restrict__ xbf,
    const unsigned short* __restrict__ W1T, const float* __restrict__ b1,
    const int* __restrict__ cnt, const int* __restrict__ toklist,
    unsigned short* __restrict__ hbuf){
  int d = blockIdx.x;
  int e = d & 7;
  int cnt_e = cnt[e];
  int row0 = (d >> 6) * BM;
  if(row0 >= cnt_e) return;
  int col0 = ((d >> 3) & 7) * 256;
  int ebase = base_of(cnt, e);
  __shared__ __align__(16) unsigned short A_s[2][BM * 64];    // 2 x 36 KB
  __shared__ __align__(16) unsigned short B_s[2][256 * 64];   // 2 x 32 KB
  __shared__ int tok_s[BM];
  int t = threadIdx.x;
  if(t < BM){
    int r = row0 + t;
    tok_s[t] = (r < cnt_e) ? toklist[e * NTOK + r] : toklist[e * NTOK + cnt_e - 1];
  }
  __syncthreads();
  int lane = t & 63, w = t >> 6;
  int wr = w >> 2, wc = w & 3;            // wave sub-tile: rows wr*144, cols wc*64
  int fr = lane & 15, fg = lane >> 4;
  int srow = t >> 3;
  int schunk = ((t & 7) ^ (srow & 7)) * 8;
  bool ahalf = t < 256;
  const unsigned short* W1e = W1T + (size_t)e * HDIM * DDIM;
  const unsigned short* aptr[5];
  const unsigned short* bptr[4];
  #pragma unroll
  for(int i = 0; i < 4; i++)
    aptr[i] = xbf + (size_t)tok_s[i * 64 + srow] * DDIM + schunk;
  aptr[4] = xbf + (size_t)tok_s[256 + (ahalf ? srow : 0)] * DDIM + schunk;
  #pragma unroll
  for(int i = 0; i < 4; i++)
    bptr[i] = W1e + (size_t)(col0 + i * 64 + srow) * DDIM + schunk;
  unsigned wbase = (unsigned)(w << 10);   // wave-uniform LDS byte base
  f32x4 acc[9][4] = {};
  KLOOP_PIPE(DDIM / 64)
  int slot0 = ebase + row0;
  #pragma unroll
  for(int m = 0; m < 9; m++){
    #pragma unroll
    for(int i = 0; i < 4; i++){
      int rr = wr*144 + m*16 + fg*4 + i;     // D: row=(lane>>4)*4+i, col=lane&15
      if(row0 + rr < cnt_e){
        size_t rowoff = (size_t)(slot0 + rr) * HDIM;
        #pragma unroll
        for(int nn = 0; nn < 4; nn++){
          int c = col0 + wc*64 + nn*16 + fr;
          float v = acc[m][nn][i] + b1[e * HDIM + c];
          hbuf[rowoff + c] = f2bf(v);
        }
      }
    }
  }
}

// ---------------- rowwise LayerNorm + exact GELU, flattened over compact slots
__global__ __launch_bounds__(256) void ln_gelu_kernel(unsigned short* __restrict__ hbuf,
    const float* __restrict__ ln_g, const float* __restrict__ ln_b,
    const int* __restrict__ cnt){
  int s = blockIdx.x;              // slot 0..2*NTOK-1, always valid (sum cnt == 2*NTOK)
  int pre = 0, e = 0;
  #pragma unroll
  for(int i = 1; i < NEXP; i++){
    pre += cnt[i-1];
    if(s >= pre) e = i;
  }
  size_t off = (size_t)s * HDIM;
  int t = threadIdx.x;
  uint4 pk = *(const uint4*)&hbuf[off + t * 8];
  float v[8];
  {
    unsigned uu[4] = {pk.x, pk.y, pk.z, pk.w};
    #pragma unroll
    for(int j = 0; j < 4; j++){
      v[2*j]   = bf2f((unsigned short)(uu[j] & 0xffffu));
      v[2*j+1] = bf2f((unsigned short)(uu[j] >> 16));
    }
  }
  float sm = 0.f, ss = 0.f;
  #pragma unroll
  for(int j = 0; j < 8; j++){ sm += v[j]; ss += v[j] * v[j]; }
  #pragma unroll
  for(int o = 32; o; o >>= 1){ sm += __shfl_xor(sm, o); ss += __shfl_xor(ss, o); }
  __shared__ float red[8];
  if((t & 63) == 0){ red[t >> 6] = sm; red[4 + (t >> 6)] = ss; }
  __syncthreads();
  sm = red[0] + red[1] + red[2] + red[3];
  ss = red[4] + red[5] + red[6] + red[7];
  float mean = sm * (1.0f / HDIM);
  float var  = ss * (1.0f / HDIM) - mean * mean;
  float rstd = rsqrtf(var + 1e-5f);
  const float* g  = ln_g + e * HDIM + t * 8;
  const float* bb = ln_b + e * HDIM + t * 8;
  unsigned ou[4];
  #pragma unroll
  for(int j = 0; j < 4; j++){
    float y0 = (v[2*j]   - mean) * rstd * g[2*j]   + bb[2*j];
    float y1 = (v[2*j+1] - mean) * rstd * g[2*j+1] + bb[2*j+1];
    y0 = 0.5f * y0 * (1.0f + erff(y0 * 0.70710678118654752f));
    y1 = 0.5f * y1 * (1.0f + erff(y1 * 0.70710678118654752f));
    ou[j] = (unsigned)f2bf(y0) | ((unsigned)f2bf(y1) << 16);
  }
  uint4 o4; o4.x = ou[0]; o4.y = ou[1]; o4.z = ou[2]; o4.w = ou[3];
  *(uint4*)&hbuf[off + t * 8] = o4;
}

// ---------------- grouped GEMM2: 288x256 tile, 8 waves, 5-phase/K-tile; linear bf16 store
__global__ __launch_bounds__(512) void gemm2_kernel(const unsigned short* __restrict__ hbuf,
    const unsigned short* __restrict__ W2T, const float* __restrict__ b2,
    const int* __restrict__ cnt, unsigned short* __restrict__ eobuf){
  int d = blockIdx.x;
  int e = d & 7;
  int cnt_e = cnt[e];
  int row0 = (d >> 6) * BM;
  if(row0 >= cnt_e) return;
  int col0 = ((d >> 3) & 7) * 256;
  int ebase = base_of(cnt, e);
  __shared__ __align__(16) unsigned short A_s[2][BM * 64];
  __shared__ __align__(16) unsigned short B_s[2][256 * 64];
  int t = threadIdx.x;
  int lane = t & 63, w = t >> 6;
  int wr = w >> 2, wc = w & 3;
  int fr = lane & 15, fg = lane >> 4;
  int srow = t >> 3;
  int schunk = ((t & 7) ^ (srow & 7)) * 8;
  bool ahalf = t < 256;
  const unsigned short* W2e = W2T + (size_t)e * HDIM * HDIM;
  const unsigned short* aptr[5];
  const unsigned short* bptr[4];
  #pragma unroll
  for(int i = 0; i < 4; i++)
    aptr[i] = hbuf + (size_t)(ebase + row0 + i * 64 + srow) * HDIM + schunk;
  aptr[4] = hbuf + (size_t)(ebase + row0 + 256 + (ahalf ? srow : 0)) * HDIM + schunk;
  #pragma unroll
  for(int i = 0; i < 4; i++)
    bptr[i] = W2e + (size_t)(col0 + i * 64 + srow) * HDIM + schunk;
  unsigned wbase = (unsigned)(w << 10);
  f32x4 acc[9][4] = {};
  KLOOP_PIPE(HDIM / 64)
  int slot0 = ebase + row0;
  #pragma unroll
  for(int m = 0; m < 9; m++){
    #pragma unroll
    for(int i = 0; i < 4; i++){
      int rr = wr*144 + m*16 + fg*4 + i;
      if(row0 + rr < cnt_e){
        size_t rowoff = (size_t)(slot0 + rr) * HDIM;
        #pragma unroll
        for(int nn = 0; nn < 4; nn++){
          int c = col0 + wc*64 + nn*16 + fr;
          float v = acc[m][nn][i] + b2[e * HDIM + c];
          eobuf[rowoff + c] = f2bf(v);
        }
      }
    }
  }
}

// ---------------- combine: out[n] = w0*eo[slot0] + w1*eo[slot1]
__global__ __launch_bounds__(256) void combine_kernel(const unsigned short* __restrict__ eobuf,
    const int* __restrict__ cnt, const int* __restrict__ se, const int* __restrict__ sp,
    const float* __restrict__ sw, float* __restrict__ out){
  int n = blockIdx.x, t = threadIdx.x;
  int pre[NEXP];
  {
    int b = 0;
    #pragma unroll
    for(int i = 0; i < NEXP; i++){ pre[i] = b; b += cnt[i]; }
  }
  int e0 = se[2*n], e1 = se[2*n+1];
  int s0 = pre[e0] + sp[2*n];
  int s1 = pre[e1] + sp[2*n+1];
  float w0 = sw[2*n], w1 = sw[2*n+1];
  uint4 p0 = *(const uint4*)&eobuf[(size_t)s0 * HDIM + t * 8];
  uint4 p1 = *(const uint4*)&eobuf[(size_t)s1 * HDIM + t * 8];
  unsigned a[4] = {p0.x, p0.y, p0.z, p0.w};
  unsigned b[4] = {p1.x, p1.y, p1.z, p1.w};
  float o[8];
  #pragma unroll
  for(int j = 0; j < 4; j++){
    o[2*j]   = w0 * bf2f((unsigned short)(a[j] & 0xffffu)) + w1 * bf2f((unsigned short)(b[j] & 0xffffu));
    o[2*j+1] = w0 * bf2f((unsigned short)(a[j] >> 16))     + w1 * bf2f((unsigned short)(b[j] >> 16));
  }
  float4 o0 = {o[0], o[1], o[2], o[3]};
  float4 o1 = {o[4], o[5], o[6], o[7]};
  float* dst = out + (size_t)n * HDIM + t * 8;
  *(float4*)dst = o0;
  *(float4*)(dst + 4) = o1;
}

extern "C" void kernel_launch(void* const* d_in, const int* in_sizes, int n_in,
                              void* d_out, int out_size, void* d_ws, size_t ws_size,
                              hipStream_t stream){
  (void)in_sizes; (void)n_in; (void)out_size; (void)ws_size;
  const float* x   = (const float*)d_in[0];
  const float* W1  = (const float*)d_in[1];
  const float* b1  = (const float*)d_in[2];
  const float* lng = (const float*)d_in[3];
  const float* lnb = (const float*)d_in[4];
  const float* W2  = (const float*)d_in[5];
  const float* b2  = (const float*)d_in[6];
  const float* Wg  = (const float*)d_in[7];
  const float* bg  = (const float*)d_in[8];
  float* out = (float*)d_out;

  char* ws = (char*)d_ws;
  size_t o = 0;
  unsigned short* W1T   = (unsigned short*)(ws + o); o += (size_t)NEXP * HDIM * DDIM * 2;      // 33.5 MB
  unsigned short* W2T   = (unsigned short*)(ws + o); o += (size_t)NEXP * HDIM * HDIM * 2;      // 67 MB
  unsigned short* hbuf  = (unsigned short*)(ws + o); o += (size_t)(NTOK * 2 + 512) * HDIM * 2; // 68 MB
  unsigned short* eobuf = (unsigned short*)(ws + o); o += (size_t)(NTOK * 2 + 512) * HDIM * 2; // 68 MB
  unsigned short* xbf   = (unsigned short*)(ws + o); o += (size_t)NTOK * DDIM * 2;             // 16.8 MB
  int*   cnt     = (int*)(ws + o);   o += 128;
  int*   toklist = (int*)(ws + o);   o += (size_t)NEXP * NTOK * 4;
  int*   se      = (int*)(ws + o);   o += (size_t)NTOK * 2 * 4;
  int*   sp      = (int*)(ws + o);   o += (size_t)NTOK * 2 * 4;
  float* sw      = (float*)(ws + o); o += (size_t)NTOK * 2 * 4;

  transpose_cvt2_kernel<<<dim3(HDIM/32, (DDIM+HDIM)/32, NEXP), 256, 0, stream>>>(W1, W2, W1T, W2T);
  gate_kernel<<<NTOK/4, 256, 0, stream>>>(x, Wg, bg, xbf, se, sw);
  build_lists_kernel<<<NEXP, 1024, 0, stream>>>(se, toklist, sp, cnt);
  // 1D grids: 8 experts x 8 col-blocks x NRMAX row-blocks (live blocks packed at low indices)
  gemm1_kernel<<<8 * 8 * NRMAX, 512, 0, stream>>>(xbf, W1T, b1, cnt, toklist, hbuf);
  ln_gelu_kernel<<<NTOK * 2, 256, 0, stream>>>(hbuf, lng, lnb, cnt);
  gemm2_kernel<<<8 * 8 * NRMAX, 512, 0, stream>>>(hbuf, W2T, b2, cnt, eobuf);
  combine_kernel<<<NTOK, 256, 0, stream>>>(eobuf, cnt, se, sp, sw, out);
}